// Round 4
// baseline (87.542 us; speedup 1.0000x reference)
//
#include <hip/hip_runtime.h>

#define TSTEPS 256
#define NOBJ   8192
#define BATCH  64
#define DEMB   32
#define DATT   128

// ws layout (bytes)
#define HW_OFF     0
#define EX_OFF     32768
#define SEGOFF_OFF 196608
#define CNT_OFF    198656
#define EMB_OFF    199168
#define WS_NEED    (EMB_OFF + 5 * NOBJ * DEMB * 4)

struct SP {
    const float* x[5]; const int* cls[5]; const int* seg[5];
    const float* W[5]; const float* bias[5];
    const float* x_ped; const float* x_ego; const float* h_ped;
    const float* Wp; const float* bp; const float* We; const float* be;
    const float* Wax; const float* Wah; const float* ba; const float* va;
    const float* W1; const float* b1; const float* W2; const float* b2;
    const float* W3; const float* b3;
    const int* t_ptr;
    float* out;
    float* hW;      // [64][128]
    float* ex;      // [5][8192]
    int* seg_off;   // [5][65]
    int* cnt;
    float* emb;     // [5][8192][32]
    int d[5];
    int use_emb;
};

__device__ __forceinline__ int load_t(const void* p) {
    unsigned w0 = *(const unsigned*)p;
    if (w0 < (unsigned)TSTEPS) return (int)w0;
    float f = __uint_as_float(w0);
    if (f >= 0.f && f < 256.f) return (int)f;
    return 8;
}

__device__ __forceinline__ float fast_tanh(float x) {
    float e = __expf(2.0f * x);
    return 1.0f - 2.0f / (e + 1.0f);
}

__device__ __forceinline__ int lower_bound(const int* a, int n, int v) {
    int lo = 0, hi = n;
    while (lo < hi) { int mid = (lo + hi) >> 1; if (a[mid] < v) lo = mid + 1; else hi = mid; }
    return lo;
}

// ---- kernel 0: hW, ped/ego feats, seg offsets, counter init
__global__ __launch_bounds__(128) void k_prep(SP p) {
    const int b = blockIdx.x;
    const int j = threadIdx.x;
    const int t = load_t(p.t_ptr);
    float a = p.ba[j];
    const float* h = p.h_ped + b * DEMB;
    #pragma unroll
    for (int k = 0; k < DEMB; ++k) a += h[k] * p.Wah[k * DATT + j];
    p.hW[b * DATT + j] = a;

    if (j < DEMB) {
        const float* xp = p.x_ped + (size_t)(b * TSTEPS + t) * 4;
        float e = p.bp[j];
        #pragma unroll
        for (int k = 0; k < 4; ++k) e += xp[k] * p.Wp[k * DEMB + j];
        p.out[64 + b * 224 + j] = fmaxf(e, 0.f);
        const float* xe = p.x_ego + (size_t)(b * TSTEPS + t) * 4;
        float g = p.be[j];
        #pragma unroll
        for (int k = 0; k < 4; ++k) g += xe[k] * p.We[k * DEMB + j];
        p.out[64 + b * 224 + 192 + j] = fmaxf(g, 0.f);
    }
    if (j < 5) p.seg_off[j * 65 + b] = lower_bound(p.seg[j], NOBJ, b);
    if (b == 63 && j >= 5 && j < 10) p.seg_off[(j - 5) * 65 + 64] = NOBJ;
    if (b == 0 && j == 10) *p.cnt = 0;
}

// ---- kernel 1: scores (2 objects/thread, 8 lanes/object) + emb to ws
__global__ __launch_bounds__(256) void k_score(SP p) {
    const int type = blockIdx.y;
    const int tid  = threadIdx.x;
    const int t    = load_t(p.t_ptr);
    const int d    = p.d[type];
    const float* __restrict__ x   = p.x[type];
    const int*   __restrict__ cls = p.cls[type];
    const int*   __restrict__ seg = p.seg[type];

    __shared__ __align__(16) float WaxT[DATT * DEMB];
    __shared__ __align__(16) float W_s[7 * DEMB];
    __shared__ __align__(16) float b_s[DEMB];

    const int o = tid >> 3;
    const int q = tid & 7;
    const int i0 = blockIdx.x * 64 + o;
    const int i1 = i0 + 32;

    // issue gathers early so latency overlaps the LDS staging
    const int c0 = cls[i0 * TSTEPS + t];
    const int c1 = cls[i1 * TSTEPS + t];
    const int b0 = seg[i0];
    const int b1 = seg[i1];
    float xv0[7], xv1[7];
    {
        const float* xr0 = x + (size_t)(i0 * TSTEPS + t) * d;
        const float* xr1 = x + (size_t)(i1 * TSTEPS + t) * d;
        for (int k = 0; k < d; ++k) { xv0[k] = xr0[k]; xv1[k] = xr1[k]; }
    }

    for (int i = tid; i < DATT * DEMB; i += 256) {
        int k = i >> 7, j = i & 127;
        WaxT[j * DEMB + k] = p.Wax[i];
    }
    for (int i = tid; i < d * DEMB; i += 256) W_s[i] = p.W[type][i];
    if (tid < DEMB) b_s[tid] = p.bias[type][tid];
    __syncthreads();

    // emb for both objects, stored rotated by q (reg slot cc = logical chunk (cc+q)&7)
    float e0[DEMB], e1[DEMB];
    const float4* b4 = (const float4*)b_s;
    #pragma unroll
    for (int cc = 0; cc < 8; ++cc) {
        const int c = (cc + q) & 7;
        float4 a0 = b4[c], a1 = b4[c];
        for (int k = 0; k < d; ++k) {
            const float4 w = *(const float4*)&W_s[k * DEMB + 4 * c];
            a0.x += xv0[k]*w.x; a0.y += xv0[k]*w.y; a0.z += xv0[k]*w.z; a0.w += xv0[k]*w.w;
            a1.x += xv1[k]*w.x; a1.y += xv1[k]*w.y; a1.z += xv1[k]*w.z; a1.w += xv1[k]*w.w;
        }
        e0[4*cc+0]=fmaxf(a0.x,0.f); e0[4*cc+1]=fmaxf(a0.y,0.f);
        e0[4*cc+2]=fmaxf(a0.z,0.f); e0[4*cc+3]=fmaxf(a0.w,0.f);
        e1[4*cc+0]=fmaxf(a1.x,0.f); e1[4*cc+1]=fmaxf(a1.y,0.f);
        e1[4*cc+2]=fmaxf(a1.z,0.f); e1[4*cc+3]=fmaxf(a1.w,0.f);
    }

    float sc0 = 0.f, sc1 = 0.f;
    const float4* hw0 = (const float4*)(p.hW + b0 * DATT + q * 16);
    const float4* hw1 = (const float4*)(p.hW + b1 * DATT + q * 16);
    const float4* va4 = (const float4*)(p.va + q * 16);
    #pragma unroll
    for (int w4 = 0; w4 < 4; ++w4) {
        const float4 h0 = hw0[w4], h1 = hw1[w4], vv = va4[w4];
        #pragma unroll
        for (int u = 0; u < 4; ++u) {
            const int j = q * 16 + w4 * 4 + u;
            const float* wrow = &WaxT[j * DEMB];
            float s0a=0.f, s0b=0.f, s1a=0.f, s1b=0.f;
            #pragma unroll
            for (int cc = 0; cc < 8; ++cc) {
                const int c = (cc + q) & 7;   // bank-group 4c disjoint across q, broadcast across o
                const float4 w = *(const float4*)&wrow[4 * c];
                s0a += e0[4*cc+0]*w.x + e0[4*cc+1]*w.y;
                s0b += e0[4*cc+2]*w.z + e0[4*cc+3]*w.w;
                s1a += e1[4*cc+0]*w.x + e1[4*cc+1]*w.y;
                s1b += e1[4*cc+2]*w.z + e1[4*cc+3]*w.w;
            }
            sc0 += fast_tanh((&h0.x)[u] + (s0a + s0b)) * (&vv.x)[u];
            sc1 += fast_tanh((&h1.x)[u] + (s1a + s1b)) * (&vv.x)[u];
        }
    }
    sc0 += __shfl_xor(sc0, 1); sc1 += __shfl_xor(sc1, 1);
    sc0 += __shfl_xor(sc0, 2); sc1 += __shfl_xor(sc1, 2);
    sc0 += __shfl_xor(sc0, 4); sc1 += __shfl_xor(sc1, 4);

    if (q == 0) {
        p.ex[type * NOBJ + i0] = (c0 != -1) ? __expf(sc0) : 0.f;
        p.ex[type * NOBJ + i1] = (c1 != -1) ? __expf(sc1) : 0.f;
    }
    if (p.use_emb) {
        // reg slot cc=0 holds logical chunk q
        if (c0 != -1)
            *(float4*)&p.emb[((size_t)type * NOBJ + i0) * DEMB + 4 * q] = make_float4(e0[0],e0[1],e0[2],e0[3]);
        if (c1 != -1)
            *(float4*)&p.emb[((size_t)type * NOBJ + i1) * DEMB + 4 * q] = make_float4(e1[0],e1[1],e1[2],e1[3]);
    }
}

// ---- kernel 2: denom + probs + feature sum; last block runs the classifier head
__global__ __launch_bounds__(256) void k_finish(SP p) {
    const int type = blockIdx.y;
    const int bseg = blockIdx.x;
    const int tid  = threadIdx.x;
    const float* __restrict__ ex = p.ex + type * NOBJ;

    __shared__ float sred[4];
    __shared__ float accred[4][DEMB];
    __shared__ float Sf_s;
    __shared__ int   last_s;
    __shared__ __align__(16) float W1_s[224 * DEMB];
    __shared__ float W2_s[DEMB * DEMB];
    __shared__ float H1[BATCH][DEMB + 1];
    __shared__ float H2[BATCH][DEMB + 1];
    __shared__ float hb[3 * DEMB];
    __shared__ __align__(16) float Wf_s[7 * DEMB];
    __shared__ float bf_s[DEMB];

    const int lo = p.seg_off[type * 65 + bseg];
    const int hi = p.seg_off[type * 65 + bseg + 1];

    if (!p.use_emb) {
        const int d = p.d[type];
        for (int i = tid; i < d * DEMB; i += 256) Wf_s[i] = p.W[type][i];
        if (tid < DEMB) bf_s[tid] = p.bias[type][tid];
        __syncthreads();
    }

    float s = 0.f;
    for (int i = lo + tid; i < hi; i += 256) s += ex[i];
    #pragma unroll
    for (int off = 32; off; off >>= 1) s += __shfl_xor(s, off);
    const int wave = tid >> 6;
    if ((tid & 63) == 0) sred[wave] = s;
    __syncthreads();
    if (tid == 0) Sf_s = fmaxf(sred[0] + sred[1] + sred[2] + sred[3], 1e-30f);
    __syncthreads();
    const float inv = 1.0f / Sf_s;

    float acc[DEMB];
    #pragma unroll
    for (int j = 0; j < DEMB; ++j) acc[j] = 0.f;
    float* pout = p.out + 64 + BATCH * 224 + type * NOBJ;
    const int t = load_t(p.t_ptr);
    const int d = p.d[type];
    for (int i = lo + tid; i < hi; i += 256) {
        const float e = ex[i];
        const float pr = e * inv;
        pout[i] = pr;
        if (e > 0.f) {
            if (p.use_emb) {
                const float4* er = (const float4*)(p.emb + ((size_t)type * NOBJ + i) * DEMB);
                #pragma unroll
                for (int c = 0; c < 8; ++c) {
                    const float4 v = er[c];
                    acc[4*c+0] += pr * v.x; acc[4*c+1] += pr * v.y;
                    acc[4*c+2] += pr * v.z; acc[4*c+3] += pr * v.w;
                }
            } else {
                float xv[7];
                const float* xr = p.x[type] + (size_t)(i * TSTEPS + t) * d;
                for (int k = 0; k < d; ++k) xv[k] = xr[k];
                #pragma unroll
                for (int j4 = 0; j4 < 8; ++j4) {
                    float4 a = *(const float4*)&bf_s[4 * j4];
                    for (int k = 0; k < d; ++k) {
                        const float4 w = *(const float4*)&Wf_s[k * DEMB + 4 * j4];
                        a.x += xv[k]*w.x; a.y += xv[k]*w.y; a.z += xv[k]*w.z; a.w += xv[k]*w.w;
                    }
                    acc[4*j4+0] += pr * fmaxf(a.x, 0.f);
                    acc[4*j4+1] += pr * fmaxf(a.y, 0.f);
                    acc[4*j4+2] += pr * fmaxf(a.z, 0.f);
                    acc[4*j4+3] += pr * fmaxf(a.w, 0.f);
                }
            }
        }
    }
    #pragma unroll
    for (int j = 0; j < DEMB; ++j)
        #pragma unroll
        for (int off = 32; off; off >>= 1)
            acc[j] += __shfl_xor(acc[j], off);
    if ((tid & 63) == 0)
        for (int j = 0; j < DEMB; ++j) accred[wave][j] = acc[j];
    __syncthreads();
    if (tid < DEMB) {
        const float f = accred[0][tid] + accred[1][tid] + accred[2][tid] + accred[3][tid];
        p.out[64 + bseg * 224 + 32 * (1 + type) + tid] = f;
    }

    // ---- last-block classifier head
    __threadfence();
    if (tid == 0) last_s = (atomicAdd(p.cnt, 1) == 5 * BATCH - 1) ? 1 : 0;
    __syncthreads();
    if (!last_s) return;
    __threadfence();  // acquire: invalidate caches before reading other blocks' feats

    for (int i = tid; i < 224 * DEMB; i += 256) W1_s[i] = p.W1[i];
    for (int i = tid; i < DEMB * DEMB; i += 256) W2_s[i] = p.W2[i];
    if (tid < DEMB) { hb[tid] = p.b1[tid]; hb[DEMB + tid] = p.b2[tid]; hb[2*DEMB + tid] = p.W3[tid]; }
    __syncthreads();

    const float* feats = p.out + 64;
    for (int idx = tid; idx < BATCH * DEMB; idx += 256) {
        int b = idx >> 5, j = idx & 31;
        float a = hb[j];
        const float4* f4 = (const float4*)(feats + b * 224);
        #pragma unroll 8
        for (int k4 = 0; k4 < 56; ++k4) {
            float4 f = f4[k4];
            a += f.x * W1_s[(4*k4+0)*DEMB + j] + f.y * W1_s[(4*k4+1)*DEMB + j]
               + f.z * W1_s[(4*k4+2)*DEMB + j] + f.w * W1_s[(4*k4+3)*DEMB + j];
        }
        H1[b][j] = fmaxf(a, 0.f);
    }
    __syncthreads();
    for (int idx = tid; idx < BATCH * DEMB; idx += 256) {
        int b = idx >> 5, j = idx & 31;
        float a = hb[DEMB + j];
        #pragma unroll
        for (int k = 0; k < DEMB; ++k) a += H1[b][k] * W2_s[k * DEMB + j];
        H2[b][j] = fmaxf(a, 0.f);
    }
    __syncthreads();
    if (tid < BATCH) {
        float a = p.b3[0];
        #pragma unroll
        for (int k = 0; k < DEMB; ++k) a += H2[tid][k] * hb[2*DEMB + k];
        p.out[tid] = a;
    }
}

extern "C" void kernel_launch(void* const* d_in, const int* in_sizes, int n_in,
                              void* d_out, int out_size, void* d_ws, size_t ws_size,
                              hipStream_t stream) {
    (void)in_sizes; (void)n_in; (void)out_size;

    SP p;
    const int xi[5] = {3, 6, 9, 12, 15};
    const int wi[5] = {20, 22, 24, 26, 28};
    const int di[5] = {4, 6, 5, 7, 7};
    for (int tp = 0; tp < 5; ++tp) {
        p.x[tp]    = (const float*)d_in[xi[tp]];
        p.cls[tp]  = (const int*)d_in[xi[tp] + 1];
        p.seg[tp]  = (const int*)d_in[xi[tp] + 2];
        p.W[tp]    = (const float*)d_in[wi[tp]];
        p.bias[tp] = (const float*)d_in[wi[tp] + 1];
        p.d[tp]    = di[tp];
    }
    p.x_ped = (const float*)d_in[0];
    p.x_ego = (const float*)d_in[1];
    p.h_ped = (const float*)d_in[2];
    p.Wp = (const float*)d_in[18]; p.bp = (const float*)d_in[19];
    p.We = (const float*)d_in[30]; p.be = (const float*)d_in[31];
    p.Wax = (const float*)d_in[32]; p.Wah = (const float*)d_in[33];
    p.ba  = (const float*)d_in[34]; p.va  = (const float*)d_in[35];
    p.W1 = (const float*)d_in[36]; p.b1 = (const float*)d_in[37];
    p.W2 = (const float*)d_in[38]; p.b2 = (const float*)d_in[39];
    p.W3 = (const float*)d_in[40]; p.b3 = (const float*)d_in[41];
    p.t_ptr = (const int*)d_in[42];
    p.out = (float*)d_out;
    char* ws = (char*)d_ws;
    p.hW      = (float*)(ws + HW_OFF);
    p.ex      = (float*)(ws + EX_OFF);
    p.seg_off = (int*)(ws + SEGOFF_OFF);
    p.cnt     = (int*)(ws + CNT_OFF);
    p.emb     = (float*)(ws + EMB_OFF);
    p.use_emb = (ws_size >= (size_t)WS_NEED) ? 1 : 0;

    hipLaunchKernelGGL(k_prep,   dim3(BATCH),            dim3(DATT), 0, stream, p);
    hipLaunchKernelGGL(k_score,  dim3(NOBJ / 64, 5),     dim3(256),  0, stream, p);
    hipLaunchKernelGGL(k_finish, dim3(BATCH, 5),         dim3(256),  0, stream, p);
}

// Round 5
// 59.890 us; speedup vs baseline: 1.4617x; 1.4617x over previous
//
#include <hip/hip_runtime.h>

#define TSTEPS 256
#define NOBJ   8192
#define BATCH  64
#define DEMB   32
#define DATT   128

// ws layout (bytes)
#define HW_OFF     0
#define EX_OFF     32768
#define SEGOFF_OFF 196608
#define EMB_OFF    199168
#define WS_NEED    (EMB_OFF + 5 * NOBJ * DEMB * 4)

struct SP {
    const float* x[5]; const int* cls[5]; const int* seg[5];
    const float* W[5]; const float* bias[5];
    const float* x_ped; const float* x_ego; const float* h_ped;
    const float* Wp; const float* bp; const float* We; const float* be;
    const float* Wax; const float* Wah; const float* ba; const float* va;
    const float* W1; const float* b1; const float* W2; const float* b2;
    const float* W3; const float* b3;
    const int* t_ptr;
    float* out;
    float* hW;      // [64][128]
    float* ex;      // [5][8192]
    int* seg_off;   // [5][65]
    float* emb;     // [5][8192][32]
    int d[5];
    int use_emb;
};

__device__ __forceinline__ int load_t(const void* p) {
    unsigned w0 = *(const unsigned*)p;
    if (w0 < (unsigned)TSTEPS) return (int)w0;
    float f = __uint_as_float(w0);
    if (f >= 0.f && f < 256.f) return (int)f;
    return 8;
}

__device__ __forceinline__ float fast_tanh(float x) {
    float e = __expf(2.0f * x);
    return 1.0f - 2.0f / (e + 1.0f);
}

__device__ __forceinline__ int lower_bound(const int* a, int n, int v) {
    int lo = 0, hi = n;
    while (lo < hi) { int mid = (lo + hi) >> 1; if (a[mid] < v) lo = mid + 1; else hi = mid; }
    return lo;
}

// ---- kernel 0: hW, ped/ego feats, seg offsets
__global__ __launch_bounds__(128) void k_prep(SP p) {
    const int b = blockIdx.x;
    const int j = threadIdx.x;
    const int t = load_t(p.t_ptr);
    float a = p.ba[j];
    const float* h = p.h_ped + b * DEMB;
    #pragma unroll
    for (int k = 0; k < DEMB; ++k) a += h[k] * p.Wah[k * DATT + j];
    p.hW[b * DATT + j] = a;

    if (j < DEMB) {
        const float* xp = p.x_ped + (size_t)(b * TSTEPS + t) * 4;
        float e = p.bp[j];
        #pragma unroll
        for (int k = 0; k < 4; ++k) e += xp[k] * p.Wp[k * DEMB + j];
        p.out[64 + b * 224 + j] = fmaxf(e, 0.f);
        const float* xe = p.x_ego + (size_t)(b * TSTEPS + t) * 4;
        float g = p.be[j];
        #pragma unroll
        for (int k = 0; k < 4; ++k) g += xe[k] * p.We[k * DEMB + j];
        p.out[64 + b * 224 + 192 + j] = fmaxf(g, 0.f);
    }
    if (j < 5) p.seg_off[j * 65 + b] = lower_bound(p.seg[j], NOBJ, b);
    if (b == 63 && j >= 5 && j < 10) p.seg_off[(j - 5) * 65 + 64] = NOBJ;
}

// ---- kernel 1 body: scores (2 objects/thread, 8 lanes/object) + emb to ws
template<int D>
__device__ __forceinline__ void score_body(const SP& p, const int type, const int t,
                                           float* WaxT, float* W_s, float* b_s) {
    const int tid = threadIdx.x;
    const float* __restrict__ x   = p.x[type];
    const int*   __restrict__ cls = p.cls[type];
    const int*   __restrict__ seg = p.seg[type];

    const int o = tid >> 3;
    const int q = tid & 7;
    const int i0 = blockIdx.x * 64 + o;
    const int i1 = i0 + 32;

    // issue gathers early so latency overlaps the LDS staging
    const int c0 = cls[i0 * TSTEPS + t];
    const int c1 = cls[i1 * TSTEPS + t];
    const int b0 = seg[i0];
    const int b1 = seg[i1];
    float xv0[D], xv1[D];
    {
        const float* xr0 = x + (size_t)(i0 * TSTEPS + t) * D;
        const float* xr1 = x + (size_t)(i1 * TSTEPS + t) * D;
        #pragma unroll
        for (int k = 0; k < D; ++k) { xv0[k] = xr0[k]; xv1[k] = xr1[k]; }
    }

    for (int i = tid; i < DATT * DEMB; i += 256) {
        int k = i >> 7, j = i & 127;
        WaxT[j * DEMB + k] = p.Wax[i];
    }
    for (int i = tid; i < D * DEMB; i += 256) W_s[i] = p.W[type][i];
    if (tid < DEMB) b_s[tid] = p.bias[type][tid];
    __syncthreads();

    // emb for both objects, stored rotated by q (reg slot cc = logical chunk (cc+q)&7)
    float e0[DEMB], e1[DEMB];
    const float4* b4 = (const float4*)b_s;
    #pragma unroll
    for (int cc = 0; cc < 8; ++cc) {
        const int c = (cc + q) & 7;
        float4 a0 = b4[c], a1 = b4[c];
        #pragma unroll
        for (int k = 0; k < D; ++k) {
            const float4 w = *(const float4*)&W_s[k * DEMB + 4 * c];
            a0.x += xv0[k]*w.x; a0.y += xv0[k]*w.y; a0.z += xv0[k]*w.z; a0.w += xv0[k]*w.w;
            a1.x += xv1[k]*w.x; a1.y += xv1[k]*w.y; a1.z += xv1[k]*w.z; a1.w += xv1[k]*w.w;
        }
        e0[4*cc+0]=fmaxf(a0.x,0.f); e0[4*cc+1]=fmaxf(a0.y,0.f);
        e0[4*cc+2]=fmaxf(a0.z,0.f); e0[4*cc+3]=fmaxf(a0.w,0.f);
        e1[4*cc+0]=fmaxf(a1.x,0.f); e1[4*cc+1]=fmaxf(a1.y,0.f);
        e1[4*cc+2]=fmaxf(a1.z,0.f); e1[4*cc+3]=fmaxf(a1.w,0.f);
    }

    float sc0 = 0.f, sc1 = 0.f;
    const float4* hw0 = (const float4*)(p.hW + b0 * DATT + q * 16);
    const float4* hw1 = (const float4*)(p.hW + b1 * DATT + q * 16);
    const float4* va4 = (const float4*)(p.va + q * 16);
    #pragma unroll
    for (int w4 = 0; w4 < 4; ++w4) {
        const float4 h0 = hw0[w4], h1 = hw1[w4], vv = va4[w4];
        #pragma unroll
        for (int u = 0; u < 4; ++u) {
            const int j = q * 16 + w4 * 4 + u;
            const float* wrow = &WaxT[j * DEMB];
            float s0a=0.f, s0b=0.f, s1a=0.f, s1b=0.f;
            #pragma unroll
            for (int cc = 0; cc < 8; ++cc) {
                const int c = (cc + q) & 7;   // bank-group 4c disjoint across q, broadcast across o
                const float4 w = *(const float4*)&wrow[4 * c];
                s0a += e0[4*cc+0]*w.x + e0[4*cc+1]*w.y;
                s0b += e0[4*cc+2]*w.z + e0[4*cc+3]*w.w;
                s1a += e1[4*cc+0]*w.x + e1[4*cc+1]*w.y;
                s1b += e1[4*cc+2]*w.z + e1[4*cc+3]*w.w;
            }
            sc0 += fast_tanh((&h0.x)[u] + (s0a + s0b)) * (&vv.x)[u];
            sc1 += fast_tanh((&h1.x)[u] + (s1a + s1b)) * (&vv.x)[u];
        }
    }
    sc0 += __shfl_xor(sc0, 1); sc1 += __shfl_xor(sc1, 1);
    sc0 += __shfl_xor(sc0, 2); sc1 += __shfl_xor(sc1, 2);
    sc0 += __shfl_xor(sc0, 4); sc1 += __shfl_xor(sc1, 4);

    if (q == 0) {
        p.ex[type * NOBJ + i0] = (c0 != -1) ? __expf(sc0) : 0.f;
        p.ex[type * NOBJ + i1] = (c1 != -1) ? __expf(sc1) : 0.f;
    }
    if (p.use_emb) {
        // reg slot cc=0 holds logical chunk q; unconditional -> emb fully defined
        *(float4*)&p.emb[((size_t)type * NOBJ + i0) * DEMB + 4 * q] = make_float4(e0[0],e0[1],e0[2],e0[3]);
        *(float4*)&p.emb[((size_t)type * NOBJ + i1) * DEMB + 4 * q] = make_float4(e1[0],e1[1],e1[2],e1[3]);
    }
}

__global__ __launch_bounds__(256) void k_score(SP p) {
    __shared__ __align__(16) float WaxT[DATT * DEMB];
    __shared__ __align__(16) float W_s[7 * DEMB];
    __shared__ __align__(16) float b_s[DEMB];
    const int t = load_t(p.t_ptr);
    switch (blockIdx.y) {
        case 0: score_body<4>(p, 0, t, WaxT, W_s, b_s); break;
        case 1: score_body<6>(p, 1, t, WaxT, W_s, b_s); break;
        case 2: score_body<5>(p, 2, t, WaxT, W_s, b_s); break;
        case 3: score_body<7>(p, 3, t, WaxT, W_s, b_s); break;
        default: score_body<7>(p, 4, t, WaxT, W_s, b_s); break;
    }
}

// ---- kernel 2: per (type,segment) wave: denom + probs + feature sum (channel/lane)
__global__ __launch_bounds__(64) void k_finish(SP p) {
    const int type = blockIdx.y;
    const int bseg = blockIdx.x;
    const int tid  = threadIdx.x;
    const float* __restrict__ ex = p.ex + type * NOBJ;
    const int lo = p.seg_off[type * 65 + bseg];
    const int hi = p.seg_off[type * 65 + bseg + 1];

    float s = 0.f;
    for (int i = lo + tid; i < hi; i += 64) s += ex[i];
    #pragma unroll
    for (int off = 32; off; off >>= 1) s += __shfl_xor(s, off);
    const float inv = 1.0f / fmaxf(s, 1e-30f);

    const int half = tid >> 5;   // half-wave picks objects; lane j owns channel j
    const int j    = tid & 31;
    float acc = 0.f;
    float* pout = p.out + 64 + BATCH * 224 + type * NOBJ;

    if (p.use_emb) {
        const float* __restrict__ eb = p.emb + (size_t)type * NOBJ * DEMB;
        #pragma unroll 2
        for (int i = lo + half; i < hi; i += 2) {
            const float pr = ex[i] * inv;
            if (j == 0) pout[i] = pr;
            acc += pr * eb[(size_t)i * DEMB + j];   // 128B coalesced line per half-wave
        }
    } else {
        const int t = load_t(p.t_ptr);
        const int d = p.d[type];
        float wj[7];
        for (int k = 0; k < d; ++k) wj[k] = p.W[type][k * DEMB + j];
        const float bj = p.bias[type][j];
        for (int i = lo + half; i < hi; i += 2) {
            const float e = ex[i];
            const float pr = e * inv;
            if (j == 0) pout[i] = pr;
            if (e > 0.f) {
                const float* xr = p.x[type] + (size_t)(i * TSTEPS + t) * d;
                float a = bj;
                for (int k = 0; k < d; ++k) a += xr[k] * wj[k];
                acc += pr * fmaxf(a, 0.f);
            }
        }
    }
    acc += __shfl_xor(acc, 32);
    if (half == 0)
        p.out[64 + bseg * 224 + 32 * (1 + type) + j] = acc;
}

// ---- kernel 3: classifier head, one wave per batch row
__global__ __launch_bounds__(64) void k_head(SP p) {
    const int b   = blockIdx.x;
    const int tid = threadIdx.x;
    const int j    = tid & 31;
    const int half = tid >> 5;
    __shared__ float h1s[DEMB];
    __shared__ float h2s[DEMB];
    const float* feats = p.out + 64 + b * 224;

    float a = 0.f;
    const int k0 = half * 112;
    #pragma unroll 4
    for (int k = k0; k < k0 + 112; ++k)
        a += feats[k] * p.W1[k * DEMB + j];
    a += __shfl_xor(a, 32);
    if (half == 0) h1s[j] = fmaxf(a + p.b1[j], 0.f);
    __syncthreads();

    float a2 = 0.f;
    const int k2 = half * 16;
    #pragma unroll
    for (int k = k2; k < k2 + 16; ++k)
        a2 += h1s[k] * p.W2[k * DEMB + j];
    a2 += __shfl_xor(a2, 32);
    if (half == 0) h2s[j] = fmaxf(a2 + p.b2[j], 0.f);
    __syncthreads();

    if (half == 0) {
        float v = h2s[j] * p.W3[j];
        v += __shfl_xor(v, 16); v += __shfl_xor(v, 8);
        v += __shfl_xor(v, 4);  v += __shfl_xor(v, 2); v += __shfl_xor(v, 1);
        if (j == 0) p.out[b] = v + p.b3[0];
    }
}

extern "C" void kernel_launch(void* const* d_in, const int* in_sizes, int n_in,
                              void* d_out, int out_size, void* d_ws, size_t ws_size,
                              hipStream_t stream) {
    (void)in_sizes; (void)n_in; (void)out_size;

    SP p;
    const int xi[5] = {3, 6, 9, 12, 15};
    const int wi[5] = {20, 22, 24, 26, 28};
    const int di[5] = {4, 6, 5, 7, 7};
    for (int tp = 0; tp < 5; ++tp) {
        p.x[tp]    = (const float*)d_in[xi[tp]];
        p.cls[tp]  = (const int*)d_in[xi[tp] + 1];
        p.seg[tp]  = (const int*)d_in[xi[tp] + 2];
        p.W[tp]    = (const float*)d_in[wi[tp]];
        p.bias[tp] = (const float*)d_in[wi[tp] + 1];
        p.d[tp]    = di[tp];
    }
    p.x_ped = (const float*)d_in[0];
    p.x_ego = (const float*)d_in[1];
    p.h_ped = (const float*)d_in[2];
    p.Wp = (const float*)d_in[18]; p.bp = (const float*)d_in[19];
    p.We = (const float*)d_in[30]; p.be = (const float*)d_in[31];
    p.Wax = (const float*)d_in[32]; p.Wah = (const float*)d_in[33];
    p.ba  = (const float*)d_in[34]; p.va  = (const float*)d_in[35];
    p.W1 = (const float*)d_in[36]; p.b1 = (const float*)d_in[37];
    p.W2 = (const float*)d_in[38]; p.b2 = (const float*)d_in[39];
    p.W3 = (const float*)d_in[40]; p.b3 = (const float*)d_in[41];
    p.t_ptr = (const int*)d_in[42];
    p.out = (float*)d_out;
    char* ws = (char*)d_ws;
    p.hW      = (float*)(ws + HW_OFF);
    p.ex      = (float*)(ws + EX_OFF);
    p.seg_off = (int*)(ws + SEGOFF_OFF);
    p.emb     = (float*)(ws + EMB_OFF);
    p.use_emb = (ws_size >= (size_t)WS_NEED) ? 1 : 0;

    hipLaunchKernelGGL(k_prep,   dim3(BATCH),         dim3(DATT), 0, stream, p);
    hipLaunchKernelGGL(k_score,  dim3(NOBJ / 64, 5),  dim3(256),  0, stream, p);
    hipLaunchKernelGGL(k_finish, dim3(BATCH, 5),      dim3(64),   0, stream, p);
    hipLaunchKernelGGL(k_head,   dim3(BATCH),         dim3(64),   0, stream, p);
}